// Round 9
// baseline (344.759 us; speedup 1.0000x reference)
//
#include <hip/hip_runtime.h>

typedef unsigned short u16;
typedef __attribute__((ext_vector_type(8))) short short8;   // 8 bf16 (4 VGPRs)
typedef __attribute__((ext_vector_type(4))) float f32x4;    // 4 fp32 acc

__device__ __forceinline__ float b2f(u16 u) { return __uint_as_float(((unsigned)u) << 16); }
__device__ __forceinline__ u16 f2b(float f) {
    unsigned x = __float_as_uint(f);
    return (u16)((x + 0x7fffu + ((x >> 16) & 1u)) >> 16);
}

// async global->LDS, 16B per lane; LDS dest = wave-uniform base + lane*16
#define GLDS16(gp, lp) __builtin_amdgcn_global_load_lds( \
    (const __attribute__((address_space(1))) void*)(gp), \
    (__attribute__((address_space(3))) void*)(lp), 16, 0, 0)

// counted vmcnt wait (T4): leave N loads in flight, don't drain
#define WAITV(N) do { \
    asm volatile("s_waitcnt vmcnt(" #N ")" ::: "memory"); \
    __builtin_amdgcn_sched_barrier(0); \
} while (0)

// Bank-conflict swizzle (rule #21, both-sides): LDS stays linear; the lane's
// GLOBAL column pick is permuted and the read applies the same XOR.
#define KC8_SWZ(lane) ((((lane) & 3) ^ (((lane) >> 3) & 3)) << 3)
#define RD_SWZ(fm, fq) (((fq) ^ (((fm) >> 1) & 3)) << 3)

// XCD swizzle (T1): pin all blocks sharing a weight panel (same bx) to one
// XCD so the 16x panel re-reads hit that XCD's 4MB L2 instead of LLC.
__device__ __forceinline__ void xcd_swz(int& bx, int& by) {
    if ((gridDim.x & 7) == 0 && gridDim.y == 16) {
        int lid = bx + by * gridDim.x;
        int q = lid >> 3, r = lid & 7;
        by = q & 15;
        bx = r + ((q >> 4) << 3);
    }
}

// ---------------------------------------------------------------------------
// Grouped MFMA GEMM: up to 4 column-segments, 2 A operands.
// Tile 64M x 64N, BK=32 stages, 6-buffer rotation, two stages per barrier
// (8 MFMAs/barrier), counted vmcnt (steady 4).  epi: 0 fp32; 1 fp32 += res
// (dual dst2); 3 bf16.
// NOTE (R7 lesson): 128-row M-tile halves block count -> net -7% at these
// M=1024 shapes.  Block count is the binding constraint; keep 64x64.
// ---------------------------------------------------------------------------
struct Seg { const u16* W; const float* bias; void* C; int ldc; int epi; int bx0; int aidx; };
struct GArgs {
    const u16* A[2]; int lda[2]; int K[2];
    Seg seg[4]; int nseg;
    const float* res;
    float* dst2;
};

__launch_bounds__(256)
__global__ void mgemm4(GArgs ga)
{
    __shared__ u16 As[6 * 2048];   // 6 bufs x [64 rows][32 k] = 24 KB
    __shared__ u16 Bs[6 * 2048];
    int bx = blockIdx.x, by = blockIdx.y;
    xcd_swz(bx, by);
    int si = 0;
#pragma unroll
    for (int i = 1; i < 4; i++)
        if (i < ga.nseg && bx >= ga.seg[i].bx0) si = i;
    const u16* Wp = ga.seg[si].W;
    const float* bp = ga.seg[si].bias;
    void* Cp = ga.seg[si].C;
    const int ldco = ga.seg[si].ldc;
    const int epi = ga.seg[si].epi;
    const int ai = ga.seg[si].aidx;
    const u16* Ap = ga.A[ai];
    const int lda = ga.lda[ai], K = ga.K[ai];
    const int col0 = (bx - ga.seg[si].bx0) * 64;
    const int row0 = by * 64;

    int tid = threadIdx.x;
    int lane = tid & 63, w = tid >> 6;
    int r0 = (w << 4) + (lane >> 2), kc8 = KC8_SWZ(lane);
    const u16* gA = Ap + (size_t)(row0 + r0) * lda + kc8;
    const u16* gB = Wp + (size_t)(col0 + r0) * lda + kc8;   // ldw == lda

    int fm = lane & 15, fq = lane >> 4;
    const int so = RD_SWZ(fm, fq);
    f32x4 acc[4] = {};

#define MG_STAGE(BS, KO) do { \
    GLDS16(gA + (KO), As + (BS) * 2048 + (w << 9)); \
    GLDS16(gB + (KO), Bs + (BS) * 2048 + (w << 9)); \
} while (0)

    const int nst = K >> 5;      // >= 8 always, even
    MG_STAGE(0, 0); MG_STAGE(1, 32); MG_STAGE(2, 64); MG_STAGE(3, 96);
    int bcur = 0;
    for (int t = 0; t < nst; t += 2) {
        if (t < nst - 2) { WAITV(4); } else { WAITV(0); }
        __builtin_amdgcn_s_barrier();
        int w4 = bcur + 4; if (w4 >= 6) w4 -= 6;
        int w5 = w4 + 1;   if (w5 >= 6) w5 -= 6;
        if (t + 4 < nst) MG_STAGE(w4, (t + 4) << 5);
        if (t + 5 < nst) MG_STAGE(w5, (t + 5) << 5);
#pragma unroll
        for (int sub = 0; sub < 2; sub++) {
            int bc = bcur + sub; if (bc >= 6) bc -= 6;
            short8 af = *(const short8*)(As + bc * 2048 + (w << 9) + fm * 32 + so);
            short8 bf[4];
#pragma unroll
            for (int nt = 0; nt < 4; nt++)
                bf[nt] = *(const short8*)(Bs + bc * 2048 + ((nt << 4) + fm) * 32 + so);
#pragma unroll
            for (int nt = 0; nt < 4; nt++)
                acc[nt] = __builtin_amdgcn_mfma_f32_16x16x32_bf16(af, bf[nt], acc[nt], 0, 0, 0);
        }
        bcur += 2; if (bcur >= 6) bcur -= 6;
    }
#undef MG_STAGE

    // C/D layout: col = lane&15, row = (lane>>4)*4 + reg   [m89/m91]
    int rbase = row0 + (w << 4) + (fq << 2);
#pragma unroll
    for (int nt = 0; nt < 4; nt++) {
        int c = col0 + (nt << 4) + fm;
        float bcol = bp[c];
#pragma unroll
        for (int reg = 0; reg < 4; reg++) {
            int r = rbase + reg;
            float v = acc[nt][reg] + bcol;
            if (epi == 3)
                ((u16*)Cp)[(size_t)r * ldco + c] = f2b(v);
            else if (epi == 1) {
                float o = v + ga.res[(size_t)r * ldco + c];
                ((float*)Cp)[(size_t)r * ldco + c] = o;
                if (ga.dst2) ga.dst2[(size_t)r * ldco + c] = o;
            } else
                ((float*)Cp)[(size_t)r * ldco + c] = v;
        }
    }
}

// ---------------------------------------------------------------------------
// mega_glu (GATED): W1 and W3 projections in one block (shared A-tile), gate
// in the epilogue, writes G = silu(U)*V only.  6-buffer 2-stage/barrier
// pipeline (16 MFMAs/barrier), counted vmcnt (steady 6).  XCD-swizzled.
// ---------------------------------------------------------------------------
__launch_bounds__(256)
__global__ void mega_glu(const u16* __restrict__ Y16,
                         const u16* __restrict__ sw1, const float* __restrict__ sb1,
                         const u16* __restrict__ sw3, const float* __restrict__ sb3,
                         const u16* __restrict__ ew1, const float* __restrict__ eb1,
                         const u16* __restrict__ ew3, const float* __restrict__ eb3,
                         u16* __restrict__ Gb,
                         const int* __restrict__ lists, const int* __restrict__ counts)
{
    __shared__ u16 As[6 * 2048];
    __shared__ u16 B1s[6 * 2048];
    __shared__ u16 B3s[6 * 2048];
    int bx = blockIdx.x, by = blockIdx.y, z = blockIdx.z;
    xcd_swz(bx, by);
    int col0 = bx * 64;
    int cnt = 1024; const int* list = nullptr;
    const u16 *W1p, *W3p; const float *b1p, *b3p;
    if (z == 0) {
        W1p = sw1; b1p = sb1; W3p = sw3; b3p = sb3;
    } else {
        int e = z - 1; cnt = counts[e]; list = lists + (e << 10);
        W1p = ew1 + (size_t)e * 512 * 1024; b1p = eb1 + e * 512;
        W3p = ew3 + (size_t)e * 512 * 1024; b3p = eb3 + e * 512;
    }
    int row0 = by * 64;
    if (row0 >= cnt) return;
    u16* Cp = Gb + (size_t)z * 524288;

    int tid = threadIdx.x, lane = tid & 63, w = tid >> 6;
    int r0 = (w << 4) + (lane >> 2), kc8 = KC8_SWZ(lane);
    int ar = row0 + r0;
    if (z > 0) ar = list[ar < cnt ? ar : cnt - 1];
    const u16* gA = Y16 + (size_t)ar * 1024 + kc8;
    const u16* gB1 = W1p + (size_t)(col0 + r0) * 1024 + kc8;
    const u16* gB3 = W3p + (size_t)(col0 + r0) * 1024 + kc8;

    int fm = lane & 15, fq = lane >> 4;
    const int so = RD_SWZ(fm, fq);
    f32x4 accU[4] = {}, accV[4] = {};

#define GL_STAGE(BS, KO) do { \
    GLDS16(gA + (KO),  As  + (BS) * 2048 + (w << 9)); \
    GLDS16(gB1 + (KO), B1s + (BS) * 2048 + (w << 9)); \
    GLDS16(gB3 + (KO), B3s + (BS) * 2048 + (w << 9)); \
} while (0)

    GL_STAGE(0, 0); GL_STAGE(1, 32); GL_STAGE(2, 64); GL_STAGE(3, 96);
    int bcur = 0;
    for (int t = 0; t < 32; t += 2) {
        if (t < 30) { WAITV(6); } else { WAITV(0); }
        __builtin_amdgcn_s_barrier();
        int w4 = bcur + 4; if (w4 >= 6) w4 -= 6;
        int w5 = w4 + 1;   if (w5 >= 6) w5 -= 6;
        if (t + 4 < 32) GL_STAGE(w4, (t + 4) << 5);
        if (t + 5 < 32) GL_STAGE(w5, (t + 5) << 5);
#pragma unroll
        for (int sub = 0; sub < 2; sub++) {
            int bc = bcur + sub; if (bc >= 6) bc -= 6;
            short8 af = *(const short8*)(As + bc * 2048 + (w << 9) + fm * 32 + so);
#pragma unroll
            for (int nt = 0; nt < 4; nt++) {
                short8 b1 = *(const short8*)(B1s + bc * 2048 + ((nt << 4) + fm) * 32 + so);
                accU[nt] = __builtin_amdgcn_mfma_f32_16x16x32_bf16(af, b1, accU[nt], 0, 0, 0);
            }
#pragma unroll
            for (int nt = 0; nt < 4; nt++) {
                short8 b3 = *(const short8*)(B3s + bc * 2048 + ((nt << 4) + fm) * 32 + so);
                accV[nt] = __builtin_amdgcn_mfma_f32_16x16x32_bf16(af, b3, accV[nt], 0, 0, 0);
            }
        }
        bcur += 2; if (bcur >= 6) bcur -= 6;
    }
#undef GL_STAGE

    int rbase = row0 + (w << 4) + (fq << 2);
#pragma unroll
    for (int nt = 0; nt < 4; nt++) {
        int c = col0 + (nt << 4) + fm;
        float b1c = b1p[c], b3c = b3p[c];
#pragma unroll
        for (int reg = 0; reg < 4; reg++) {
            int r = rbase + reg;
            if (r >= cnt) continue;
            float u = b2f(f2b(accU[nt][reg] + b1c));   // bf16 round-trip:
            float v = b2f(f2b(accV[nt][reg] + b3c));   // bit-identical to old
            Cp[(size_t)r * 512 + c] = f2b(u / (1.f + __expf(-u)) * v);
        }
    }
}

// ---------------------------------------------------------------------------
// mega_down: Dscr[z] = G[z] @ W2^T + b2.  Pure GEMM, NO atomics, NO gather
// (scratch is position-indexed; ffn_combine applies gates and sums).
// 6-buffer 2-stage/barrier pipeline.  XCD-swizzled.
// ---------------------------------------------------------------------------
__launch_bounds__(256)
__global__ void mega_down(const u16* __restrict__ Gb,
                          const u16* __restrict__ sw2, const float* __restrict__ sb2,
                          const u16* __restrict__ ew2, const float* __restrict__ eb2,
                          float* __restrict__ Dscr,
                          const int* __restrict__ counts)
{
    __shared__ u16 Gs[6 * 2048];
    __shared__ u16 Ws[6 * 2048];
    int bx = blockIdx.x, by = blockIdx.y, z = blockIdx.z;
    xcd_swz(bx, by);
    int cnt = 1024;
    const u16* Wp; const float* bp;
    if (z == 0) { Wp = sw2; bp = sb2; }
    else {
        int e = z - 1;
        cnt = counts[e];
        Wp = ew2 + (size_t)e * 1024 * 512; bp = eb2 + e * 1024;
    }
    int row0 = by * 64;
    if (row0 >= cnt) return;
    const u16* Ap = Gb + (size_t)z * 524288;
    int col0 = bx * 64;
    float* Dp = Dscr + (size_t)z * 1048576;

    int tid = threadIdx.x, lane = tid & 63, w = tid >> 6;
    int r0 = (w << 4) + (lane >> 2), kc8 = KC8_SWZ(lane);
    const u16* gG = Ap + (size_t)(row0 + r0) * 512 + kc8;
    const u16* gW = Wp + (size_t)(col0 + r0) * 512 + kc8;

    int fm = lane & 15, fq = lane >> 4;
    const int so = RD_SWZ(fm, fq);
    f32x4 acc[4] = {};

#define MD_STAGE(BS, KO) do { \
    GLDS16(gG + (KO), Gs + (BS) * 2048 + (w << 9)); \
    GLDS16(gW + (KO), Ws + (BS) * 2048 + (w << 9)); \
} while (0)

    MD_STAGE(0, 0); MD_STAGE(1, 32); MD_STAGE(2, 64); MD_STAGE(3, 96);
    int bcur = 0;
    for (int t = 0; t < 16; t += 2) {
        if (t < 14) { WAITV(4); } else { WAITV(0); }
        __builtin_amdgcn_s_barrier();
        int w4 = bcur + 4; if (w4 >= 6) w4 -= 6;
        int w5 = w4 + 1;   if (w5 >= 6) w5 -= 6;
        if (t + 4 < 16) MD_STAGE(w4, (t + 4) << 5);
        if (t + 5 < 16) MD_STAGE(w5, (t + 5) << 5);
#pragma unroll
        for (int sub = 0; sub < 2; sub++) {
            int bc = bcur + sub; if (bc >= 6) bc -= 6;
            short8 af = *(const short8*)(Gs + bc * 2048 + (w << 9) + fm * 32 + so);
            short8 bf[4];
#pragma unroll
            for (int nt = 0; nt < 4; nt++)
                bf[nt] = *(const short8*)(Ws + bc * 2048 + ((nt << 4) + fm) * 32 + so);
#pragma unroll
            for (int nt = 0; nt < 4; nt++)
                acc[nt] = __builtin_amdgcn_mfma_f32_16x16x32_bf16(af, bf[nt], acc[nt], 0, 0, 0);
        }
        bcur += 2; if (bcur >= 6) bcur -= 6;
    }
#undef MD_STAGE

    int rbase = row0 + (w << 4) + (fq << 2);
#pragma unroll
    for (int nt = 0; nt < 4; nt++) {
        int c = col0 + (nt << 4) + fm;
        float bcol = bp[c];
#pragma unroll
        for (int reg = 0; reg < 4; reg++) {
            int r = rbase + reg;   // rows >= cnt: garbage, never read
            Dp[(size_t)r * 1024 + c] = acc[nt][reg] + bcol;
        }
    }
}

// ffn combine: out[t] += Dsh[t] + g0*De[e0][p0] + g1*De[e1][p1].  1024 blocks.
__launch_bounds__(256)
__global__ void ffn_combine(const float* __restrict__ Dscr,
                            const int* __restrict__ sE, const int* __restrict__ sP,
                            const float* __restrict__ sG,
                            float* __restrict__ out)
{
    int t = blockIdx.x, tid = threadIdx.x;
    int e0 = sE[t * 2], e1 = sE[t * 2 + 1];
    int p0 = sP[t * 2], p1 = sP[t * 2 + 1];
    float g0 = sG[t * 2], g1 = sG[t * 2 + 1];
    const float4* Ds = (const float4*)(Dscr + (size_t)t * 1024);
    const float4* D0 = (const float4*)(Dscr + (size_t)(e0 + 1) * 1048576 + (size_t)p0 * 1024);
    const float4* D1 = (const float4*)(Dscr + (size_t)(e1 + 1) * 1048576 + (size_t)p1 * 1024);
    float4* o = (float4*)(out + (size_t)t * 1024);
    float4 a = o[tid], s = Ds[tid], x0 = D0[tid], x1 = D1[tid];
    a.x += s.x + g0 * x0.x + g1 * x1.x;
    a.y += s.y + g0 * x0.y + g1 * x1.y;
    a.z += s.z + g0 * x0.z + g1 * x1.z;
    a.w += s.w + g0 * x0.w + g1 * x1.w;
    o[tid] = a;
}

// ---------------------------------------------------------------------------
// MFMA flash attention, 64-wide K-tiles, 4-way KV-SPLIT over blockIdx.z
// (z in [0,4)), PLUS FFN-weight cast blocks (z in [4,12)): the cast is
// independent BW-heavy work that overlaps the latency-bound attention
// (450 GB/s, 5% HBM) inside one launch, removing ~13 us from the front
// fused_cast on the critical path.  mega_glu consumes the casted weights
// 4 launches later.  Each attention z-chunk writes unnormalized fp32 O +
// (m,l); attn_combine4 merges exactly.
// ---------------------------------------------------------------------------
__launch_bounds__(256)
__global__ void attn_mfma(const u16* __restrict__ Qp, const u16* __restrict__ Kp,
                          const u16* __restrict__ VT,
                          float* __restrict__ Opart, float* __restrict__ MLp,
                          const float* __restrict__ fsw1, const float* __restrict__ fsw3,
                          const float* __restrict__ fsw2, const float* __restrict__ few1,
                          const float* __restrict__ few3, const float* __restrict__ few2,
                          u16* __restrict__ warena)
{
    const int qt = blockIdx.x, h = blockIdx.y, z = blockIdx.z;
    if (z >= 4) {
        // ---- FFN weight cast: arena range [3801088, 17956864) ----
        int cb = (z - 4) * 128 + h * 16 + qt;        // 0..1023
        const int NQ4 = (17956864 - 3801088) / 4;    // 3538944 float4s
        for (int i = cb * 256 + threadIdx.x; i < NQ4; i += 1024 * 256) {
            int e = 3801088 + i * 4;
            const float* s; int base;
            if      (e <  4325376) { s = fsw1; base =  3801088; }
            else if (e <  4849664) { s = fsw3; base =  4325376; }
            else if (e <  5373952) { s = fsw2; base =  4849664; }
            else if (e <  9568256) { s = few1; base =  5373952; }
            else if (e < 13762560) { s = few3; base =  9568256; }
            else                   { s = few2; base = 13762560; }
            float4 v = *(const float4*)(s + (e - base));
            ushort4 o;
            o.x = f2b(v.x); o.y = f2b(v.y); o.z = f2b(v.z); o.w = f2b(v.w);
            *(ushort4*)(warena + e) = o;
        }
        return;
    }
    const int q0 = qt * 64;
    const int tid = threadIdx.x;
    const int lane = tid & 63, w = tid >> 6;
    const int fm = lane & 15, fq = lane >> 4;

    __shared__ u16 Ks[12288];   // 6 chunks x [64 kv][32 k]  (24 KB)
    __shared__ u16 Vs[8192];    // 2 kc x [128 d][32 kv]     (16 KB)
    __shared__ u16 Ps[4096];    // per wave: [2 kc][16 m][32 kv] (8 KB)

    const u16* qrow = Qp + ((size_t)h * 1024 + q0 + w * 16 + fm) * 192;
    short8 qf[6];
#pragma unroll
    for (int c = 0; c < 6; c++)
        qf[c] = *(const short8*)(qrow + c * 32 + fq * 8);

    const u16* Kb = Kp + (size_t)h * 1024 * 192;
    const u16* Vb = VT + (size_t)h * 128 * 1024;

    float m_i[4], l_i[4];
#pragma unroll
    for (int r = 0; r < 4; r++) { m_i[r] = -1e30f; l_i[r] = 0.f; }
    f32x4 accO[8] = {};
    const float scale = 0.07216878364870323f;  // 1/sqrt(192)
    const int nt64 = qt + 1;                   // 64-wide tiles needed
    const int ktlo = (z * nt64) >> 2;
    const int kthi = ((z + 1) * nt64) >> 2;
    const int rbase = w * 16 + fq * 4;

    for (int kt = ktlo; kt < kthi; ++kt) {
        const int o = kt * 64;
#pragma unroll
        for (int i = 0; i < 6; i++) {
            int idx = w + 4 * i;                 // 0..23
            int c = idx >> 2, k4 = idx & 3;
            const u16* g = Kb + (size_t)(o + k4 * 16 + (lane >> 2)) * 192 + c * 32 + (lane & 3) * 8;
            GLDS16(g, Ks + c * 2048 + k4 * 512 + lane * 8);
        }
#pragma unroll
        for (int i = 0; i < 4; i++) {
            int idx = w + 4 * i;                 // 0..15
            int kc = idx >> 3, k8 = idx & 7;
            const u16* g = Vb + (size_t)(k8 * 16 + (lane >> 2)) * 1024 + o + kc * 32 + (lane & 3) * 8;
            GLDS16(g, Vs + kc * 4096 + k8 * 512 + lane * 8);
        }
        __syncthreads();
        // ---- S = Q K^T (24 MFMAs over 64 cols) ----
        f32x4 sacc[4];
        __builtin_amdgcn_s_setprio(1);
#pragma unroll
        for (int nt = 0; nt < 4; nt++) {
            sacc[nt] = (f32x4){0.f, 0.f, 0.f, 0.f};
#pragma unroll
            for (int c = 0; c < 6; c++) {
                short8 kf = *(const short8*)(Ks + c * 2048 + (nt * 16 + fm) * 32 + fq * 8);
                sacc[nt] = __builtin_amdgcn_mfma_f32_16x16x32_bf16(qf[c], kf, sacc[nt], 0, 0, 0);
            }
        }
        __builtin_amdgcn_s_setprio(0);
        // ---- online softmax (mask: global col index > q row) ----
        float pv[4][4], rmax[4];
#pragma unroll
        for (int reg = 0; reg < 4; reg++) {
            int q = q0 + rbase + reg;
            float mx = -1e30f;
#pragma unroll
            for (int nt = 0; nt < 4; nt++) {
                int gk = o + nt * 16 + fm;
                float s = sacc[nt][reg] * scale;
                if (gk > q) s = -1e30f;
                pv[nt][reg] = s;
                mx = fmaxf(mx, s);
            }
            rmax[reg] = mx;
        }
#pragma unroll
        for (int m = 1; m < 16; m <<= 1)
#pragma unroll
            for (int reg = 0; reg < 4; reg++)
                rmax[reg] = fmaxf(rmax[reg], __shfl_xor(rmax[reg], m));
        float alpha[4], rsum[4];
#pragma unroll
        for (int reg = 0; reg < 4; reg++) {
            float mn = fmaxf(m_i[reg], rmax[reg]);
            alpha[reg] = __expf(m_i[reg] - mn);
            m_i[reg] = mn;
            float s = 0.f;
#pragma unroll
            for (int nt = 0; nt < 4; nt++) {
                float p = __expf(pv[nt][reg] - mn);
                pv[nt][reg] = p;
                s += p;
            }
            rsum[reg] = s;
        }
#pragma unroll
        for (int m = 1; m < 16; m <<= 1)
#pragma unroll
            for (int reg = 0; reg < 4; reg++)
                rsum[reg] += __shfl_xor(rsum[reg], m);
#pragma unroll
        for (int reg = 0; reg < 4; reg++)
            l_i[reg] = l_i[reg] * alpha[reg] + rsum[reg];
        // ---- P (C-layout) -> LDS (A-layout, bf16); per-wave slice ----
#pragma unroll
        for (int nt = 0; nt < 4; nt++)
#pragma unroll
            for (int reg = 0; reg < 4; reg++)
                Ps[w * 1024 + (nt >> 1) * 512 + (fq * 4 + reg) * 32 + (nt & 1) * 16 + fm]
                    = f2b(pv[nt][reg]);
        // ---- rescale O, then O += P V (16 MFMAs) ----
#pragma unroll
        for (int n2 = 0; n2 < 8; n2++)
#pragma unroll
            for (int reg = 0; reg < 4; reg++)
                accO[n2][reg] *= alpha[reg];
        short8 pf[2];
#pragma unroll
        for (int kc = 0; kc < 2; kc++)
            pf[kc] = *(const short8*)(Ps + w * 1024 + kc * 512 + fm * 32 + fq * 8);
        __builtin_amdgcn_s_setprio(1);
#pragma unroll
        for (int n2 = 0; n2 < 8; n2++)
#pragma unroll
            for (int kc = 0; kc < 2; kc++) {
                short8 vf = *(const short8*)(Vs + kc * 4096 + (n2 * 16 + fm) * 32 + fq * 8);
                accO[n2] = __builtin_amdgcn_mfma_f32_16x16x32_bf16(pf[kc], vf, accO[n2], 0, 0, 0);
            }
        __builtin_amdgcn_s_setprio(0);
        __syncthreads();
    }
    // ---- write unnormalized partial O (fp32) + (m,l) ----
    float* Ob = Opart + ((size_t)(z * 8 + h) * 1024) * 128;
#pragma unroll
    for (int reg = 0; reg < 4; reg++) {
        int row = q0 + rbase + reg;
#pragma unroll
        for (int n2 = 0; n2 < 8; n2++)
            Ob[(size_t)row * 128 + n2 * 16 + fm] = accO[n2][reg];
        if (fm == 0) {
            MLp[((size_t)(z * 8 + h) * 1024 + row) * 2]     = m_i[reg];
            MLp[((size_t)(z * 8 + h) * 1024 + row) * 2 + 1] = l_i[reg];
        }
    }
}

// exact online-softmax merge of the four KV-split partials -> bf16 ATT16
__launch_bounds__(256)
__global__ void attn_combine4(const float* __restrict__ Opart,
                              const float* __restrict__ MLp,
                              u16* __restrict__ O)
{
    int tid = threadIdx.x;
    int rowg = blockIdx.x * 16 + (tid >> 4);        // 0..8191 = h*1024+row
    int h = rowg >> 10, row = rowg & 1023;
    int c0 = (tid & 15) * 8;
    float m[4], l[4];
    float M = -1e30f;
#pragma unroll
    for (int z = 0; z < 4; z++) {
        m[z] = MLp[((size_t)(z * 8 + h) * 1024 + row) * 2];
        l[z] = MLp[((size_t)(z * 8 + h) * 1024 + row) * 2 + 1];
        M = fmaxf(M, m[z]);
    }
    float wz[4], den = 0.f;
#pragma unroll
    for (int z = 0; z < 4; z++) { wz[z] = __expf(m[z] - M); den += l[z] * wz[z]; }
    float inv = 1.f / den;
#pragma unroll
    for (int j = 0; j < 8; j++) {
        float o = 0.f;
#pragma unroll
        for (int z = 0; z < 4; z++)
            o += Opart[((size_t)(z * 8 + h) * 1024 + row) * 128 + c0 + j] * wz[z];
        O[(size_t)row * 1024 + h * 128 + c0 + j] = f2b(o * inv);
    }
}

// two rmsnorms (bf16 out) in one launch
__launch_bounds__(256)
__global__ void rmsnorm2x(const float* __restrict__ X0, const float* __restrict__ w0,
                          u16* __restrict__ O0, int c0,
                          const float* __restrict__ X1, const float* __restrict__ w1,
                          u16* __restrict__ O1, int c1)
{
    int b = blockIdx.x, tid = threadIdx.x;
    const float* X; const float* w; u16* O; int cols; int r;
    if (b < 1024) { X = X0; w = w0; O = O0; cols = c0; r = b; }
    else          { X = X1; w = w1; O = O1; cols = c1; r = b - 1024; }
    const float* xr = X + (size_t)r * cols;
    float ss = 0.f;
    for (int j = tid; j < cols; j += 256) { float v = xr[j]; ss += v * v; }
    __shared__ float red[256];
    red[tid] = ss; __syncthreads();
    for (int st = 128; st > 0; st >>= 1) { if (tid < st) red[tid] += red[tid + st]; __syncthreads(); }
    float scale = rsqrtf(red[0] / cols + 1e-6f);
    for (int j = tid; j < cols; j += 256)
        O[(size_t)r * cols + j] = f2b(xr[j] * scale * w[j]);
}

// ---------------------------------------------------------------------------
// rmsnorm_route: blocks [0,1024): Y16 = bf16(rmsnorm(X1,ffn_w)); blocks
// [1024,2048): routing; also records per-token (expert,pos,gate) slots for
// ffn_combine.
// ---------------------------------------------------------------------------
__launch_bounds__(256)
__global__ void rmsnorm_route(const float* __restrict__ X1, const float* __restrict__ ffnw,
                              u16* __restrict__ Y16,
                              const float* __restrict__ cent, const float* __restrict__ biases,
                              int* __restrict__ counts, int* __restrict__ lists,
                              int* __restrict__ sE, int* __restrict__ sP,
                              float* __restrict__ sG)
{
    __shared__ float red[256];
    int b = blockIdx.x, tid = threadIdx.x;
    if (b < 1024) {
        int r = b;
        const float* xr = X1 + (size_t)r * 1024;
        float ss = 0.f;
        for (int j = tid; j < 1024; j += 256) { float v = xr[j]; ss += v * v; }
        red[tid] = ss; __syncthreads();
        for (int st = 128; st > 0; st >>= 1) { if (tid < st) red[tid] += red[tid + st]; __syncthreads(); }
        float scale = rsqrtf(red[0] / 1024.f + 1e-6f);
        for (int j = tid; j < 1024; j += 256)
            Y16[(size_t)r * 1024 + j] = f2b(xr[j] * scale * ffnw[j]);
    } else {
        int t = b - 1024;
        const float* xr = X1 + (size_t)t * 1024;
        float ss = 0.f;
        float acc[8] = {};
        for (int j = tid; j < 1024; j += 256) {
            float x = xr[j];
            ss += x * x;
            float yp = x * ffnw[j];
#pragma unroll
            for (int e = 0; e < 8; e++) acc[e] += yp * cent[e * 1024 + j];
        }
        red[tid] = ss; __syncthreads();
        for (int st = 128; st > 0; st >>= 1) { if (tid < st) red[tid] += red[tid + st]; __syncthreads(); }
        float scale = rsqrtf(red[0] / 1024.f + 1e-6f);
        __syncthreads();
        __shared__ float aff[8];
        for (int e = 0; e < 8; e++) {
            red[tid] = acc[e]; __syncthreads();
            for (int st = 128; st > 0; st >>= 1) { if (tid < st) red[tid] += red[tid + st]; __syncthreads(); }
            if (tid == 0) aff[e] = 1.f / (1.f + expf(-red[0] * scale));
            __syncthreads();
        }
        if (tid == 0) {
            float sb[8];
#pragma unroll
            for (int e = 0; e < 8; e++) sb[e] = aff[e] + biases[e];
            int i0 = 0;
            for (int e = 1; e < 8; e++) if (sb[e] > sb[i0]) i0 = e;
            int i1 = -1;
            for (int e = 0; e < 8; e++) { if (e == i0) continue; if (i1 < 0 || sb[e] > sb[i1]) i1 = e; }
            float a0 = aff[i0], a1 = aff[i1];
            float mx = fmaxf(a0, a1);
            float e0 = expf(a0 - mx), e1 = expf(a1 - mx);
            float inv = 1.f / (e0 + e1);
            int p0 = atomicAdd(&counts[i0], 1);
            lists[i0 * 1024 + p0] = t;
            int p1 = atomicAdd(&counts[i1], 1);
            lists[i1 * 1024 + p1] = t;
            sE[t * 2] = i0; sP[t * 2] = p0; sG[t * 2] = e0 * inv;
            sE[t * 2 + 1] = i1; sP[t * 2 + 1] = p1; sG[t * 2 + 1] = e1 * inv;
        }
    }
}

// ---------------------------------------------------------------------------
// pack_all: blocks [0,1024): KR rmsnorm+rope, pack Q (QR rope) and K.
// Blocks [1024,1280): transpose V (bf16 [s][d] -> [d][s]).
// ---------------------------------------------------------------------------
__launch_bounds__(256)
__global__ void pack_all(const float* __restrict__ QC, const float* __restrict__ QRr,
                         const float* __restrict__ KRraw, const float* __restrict__ krw,
                         const float* __restrict__ KC,
                         const u16* __restrict__ VCb,
                         const float* __restrict__ fcos, const float* __restrict__ fsin,
                         u16* __restrict__ Qp, u16* __restrict__ Kp, u16* __restrict__ VT)
{
    __shared__ u16 Ts[64][68];
    __shared__ float kshared[64];
    int b = blockIdx.x, tid = threadIdx.x;
    if (b < 1024) {
        int s = b;
        if (tid < 64) {
            float v = KRraw[(size_t)s * 64 + tid];
            float ss = v * v;
#pragma unroll
            for (int m = 1; m < 64; m <<= 1) ss += __shfl_xor(ss, m);
            float scale = rsqrtf(ss / 64.f + 1e-6f);
            int j = tid >> 1;
            float c = fcos[s * 32 + j], sn = fsin[s * 32 + j];
            float x0 = KRraw[(size_t)s * 64 + (tid & ~1)] * scale * krw[tid & ~1];
            float x1 = KRraw[(size_t)s * 64 + (tid | 1)]  * scale * krw[tid | 1];
            kshared[tid] = (tid & 1) ? (x0 * sn + x1 * c) : (x0 * c - x1 * sn);
        }
        __syncthreads();
        for (int e = tid; e < 1536; e += 256) {
            int h = e / 192, d = e % 192;
            float q;
            if (d < 128) {
                q = QC[(size_t)s * 1024 + h * 128 + d];
            } else {
                int dd = d - 128, j = dd >> 1;
                float c = fcos[s * 32 + j], sn = fsin[s * 32 + j];
                float x0 = QRr[(size_t)s * 512 + h * 64 + (dd & ~1)];
                float x1 = QRr[(size_t)s * 512 + h * 64 + (dd | 1)];
                q = (dd & 1) ? (x0 * sn + x1 * c) : (x0 * c - x1 * sn);
            }
            Qp[((size_t)h * 1024 + s) * 192 + d] = f2b(q);
            float k = (d < 64) ? kshared[d]
                               : KC[(size_t)s * 1024 + h * 128 + d - 64];
            Kp[((size_t)h * 1024 + s) * 192 + d] = f2b(k);
        }
    } else {
        int idx = b - 1024;
        int s0 = (idx & 15) * 64, d0 = (idx >> 4) * 64;
        for (int k = 0; k < 16; k++) {
            int e = tid + k * 256, r = e >> 6, c = e & 63;
            Ts[r][c] = VCb[(size_t)(s0 + r) * 1024 + d0 + c];
        }
        __syncthreads();
        for (int k = 0; k < 16; k++) {
            int e = tid + k * 256, d = e >> 6, s = e & 63;
            VT[(size_t)(d0 + d) * 1024 + s0 + s] = Ts[s][d];
        }
    }
}

// ---------------------------------------------------------------------------
// fused_cast (ATTENTION-ONLY): fp32->bf16 cast of the attention-path weights
// (wq,wkv,wqc,wqr,wkc,wvc,wo + wkr at arena tail) + the X rmsnorm (blocks >=
// NCAST) + zeroing of counts[8].  FFN weights are cast inside the attn_mfma
// launch (overlapped with latency-bound attention).
// ---------------------------------------------------------------------------
#define NCAST 1024
__launch_bounds__(256)
__global__ void fused_cast(const float* p0, const float* p1, const float* p2,
                           const float* p3, const float* p4, const float* p5,
                           const float* p6, const float* pkr,
                           u16* __restrict__ dst,
                           const float* __restrict__ hX, const float* __restrict__ attnw,
                           u16* __restrict__ X16, int* __restrict__ zc)
{
    __shared__ float red[256];
    int b = blockIdx.x, tid = threadIdx.x;
    if (b < NCAST) {
        const int NQ = 3866624 / 4;    // 3801088 attn weights + 65536 wkr
        for (int i = b * 256 + tid; i < NQ; i += NCAST * 256) {
            int e = i * 4;
            const float* s; int base; int dstoff;
            if      (e <   786432) { s = p0;  base = 0;       dstoff = e; }
            else if (e <  1048576) { s = p1;  base =  786432; dstoff = e; }
            else if (e <  1835008) { s = p2;  base = 1048576; dstoff = e; }
            else if (e <  2228224) { s = p3;  base = 1835008; dstoff = e; }
            else if (e <  2490368) { s = p4;  base = 2228224; dstoff = e; }
            else if (e <  2752512) { s = p5;  base = 2490368; dstoff = e; }
            else if (e <  3801088) { s = p6;  base = 2752512; dstoff = e; }
            else { s = pkr; base = 3801088; dstoff = 17956864 + (e - 3801088); }
            float4 v = *(const float4*)(s + (e - base));
            ushort4 o;
            o.x = f2b(v.x); o.y = f2b(v.y); o.z = f2b(v.z); o.w = f2b(v.w);
            *(ushort4*)(dst + dstoff) = o;
        }
    } else {
        int r = b - NCAST;
        if (r == 0 && tid < 8) zc[tid] = 0;   // counts[8]
        const float* xr = hX + (size_t)r * 1024;
        float ss = 0.f;
        for (int j = tid; j < 1024; j += 256) { float v = xr[j]; ss += v * v; }
        red[tid] = ss; __syncthreads();
        for (int st = 128; st > 0; st >>= 1) { if (tid < st) red[tid] += red[tid + st]; __syncthreads(); }
        float scale = rsqrtf(red[0] / 1024.f + 1e-6f);
        for (int j = tid; j < 1024; j += 256)
            X16[(size_t)r * 1024 + j] = f2b(xr[j] * scale * attnw[j]);
    }
}

// ---------------------------------------------------------------------------
extern "C" void kernel_launch(void* const* d_in, const int* in_sizes, int n_in,
                              void* d_out, int out_size, void* d_ws, size_t ws_size,
                              hipStream_t stream)
{
    (void)in_sizes; (void)n_in; (void)ws_size; (void)out_size;
    const float* h       = (const float*)d_in[0];
    const float* fcos    = (const float*)d_in[1];
    const float* fsin    = (const float*)d_in[2];
    const float* attn_w  = (const float*)d_in[4];
    const float* ffn_w   = (const float*)d_in[5];
    const float* wq_down = (const float*)d_in[6];
    const float* bq_down = (const float*)d_in[7];
    const float* q_norm  = (const float*)d_in[8];
    const float* wqc     = (const float*)d_in[9];
    const float* bqc     = (const float*)d_in[10];
    const float* wqr     = (const float*)d_in[11];
    const float* bqr     = (const float*)d_in[12];
    const float* wkr     = (const float*)d_in[13];
    const float* bkr     = (const float*)d_in[14];
    const float* kr_norm = (const float*)d_in[15];
    const float* wkv     = (const float*)d_in[16];
    const float* bkv     = (const float*)d_in[17];
    const float* kv_norm = (const float*)d_in[18];
    const float* wkc     = (const float*)d_in[19];
    const float* bkc     = (const float*)d_in[20];
    const float* wvc     = (const float*)d_in[21];
    const float* bvc     = (const float*)d_in[22];
    const float* wo      = (const float*)d_in[23];
    const float* bo      = (const float*)d_in[24];
    const float* sw1     = (const float*)d_in[25];
    const float* sb1     = (const float*)d_in[26];
    const float* sw2     = (const float*)d_in[27];
    const float* sb2     = (const float*)d_in[28];
    const float* sw3     = (const float*)d_in[29];
    const float* sb3     = (const float*)d_in[30];
    const float* ew1     = (const float*)d_in[31];
    const float* eb1     = (const float*)d_in[32];
    const float* ew2     = (const float*)d_in[33];
    const float* eb2     = (const float*)d_in[34];
    const float* ew3     = (const float*)d_in[35];
    const float* eb3     = (const float*)d_in[36];
    const float* cent    = (const float*)d_in[37];
    const float* biases  = (const float*)d_in[38];

    char* wsb = (char*)d_ws;
    const size_t U5 = 512 * 1024;  // 0.5 MB unit
    u16*   X16   = (u16*)(wsb + 8 * U5);       // 2 MB
    float* QRr   = (float*)(wsb + 12 * U5);    // 2 MB
    float* CQraw = (float*)(wsb + 16 * U5);    // 3 MB (early)
    u16*   ATT16 = (u16*)(wsb + 16 * U5);      // 2 MB (after CQraw dead)
    u16*   CQ16  = (u16*)(wsb + 22 * U5);      // 1.5 MB
    float* CKVraw= (float*)(wsb + 25 * U5);    // 1 MB
    u16*   CKV16 = (u16*)(wsb + 27 * U5);      // 0.5 MB
    float* KRraw = (float*)(wsb + 28 * U5);    // 0.25 MB
    float* QC    = (float*)(wsb + 29 * U5);    // 4 MB (dead after pack)
    float* KC    = (float*)(wsb + 37 * U5);    // 4 MB (dead after pack)
    float* X1    = (float*)(wsb + 53 * U5);    // 4 MB
    int*   counts= (int*)(wsb + 61 * U5 + 64 * 1024);
    int*   lists = (int*)(wsb + 61 * U5 + 32 * 1024);
    int*   sE    = (int*)(wsb + 61 * U5 + 72 * 1024);   // 8 KB
    int*   sP    = (int*)(wsb + 61 * U5 + 80 * 1024);   // 8 KB
    float* sG    = (float*)(wsb + 61 * U5 + 88 * 1024); // 8 KB
    u16*   Y16   = (u16*)(wsb + 69 * U5);      // 2 MB
    u16*   Gb    = (u16*)(wsb + 73 * U5);      // 9 MB gated GLU output (73..90)

    // bf16 weight arena (contiguous; attn block [0,3801088), FFN block
    // [3801088,17956864), wkr tail [17956864,18022400))
    u16* wb = (u16*)(wsb + 92 * U5);
    u16 *c_wq  = wb;
    u16 *c_wkv = c_wq  + 786432;
    u16 *c_wqc = c_wkv + 262144;
    u16 *c_wqr = c_wqc + 786432;
    u16 *c_wkc = c_wqr + 393216;
    u16 *c_wvc = c_wkc + 262144;
    u16 *c_wo  = c_wvc + 262144;
    u16 *c_sw1 = c_wo  + 1048576;
    u16 *c_sw3 = c_sw1 + 524288;
    u16 *c_sw2 = c_sw3 + 524288;
    u16 *c_ew1 = c_sw2 + 524288;
    u16 *c_ew3 = c_ew1 + 4194304;
    u16 *c_ew2 = c_ew3 + 4194304;
    u16 *c_wkr = c_ew2 + 4194304;                 // 64x1024 (exact)
    u16* VCb = (u16*)(wsb + 92 * U5 + 36175872);  // 2 MB bf16 V [s][d]
    u16* VTp = VCb + 1048576;                     // 2 MB bf16 V^T [d][s]
    u16* Qpk = VTp + 1048576;                     // 3 MB
    u16* Kpk = Qpk + 1572864;                     // 3 MB
    // scratch (ws ~268 MB)
    float* Opart = (float*)(wsb + 192 * U5);      // 16 MB [4][8][1024][128] f32
    float* Dscr  = (float*)(wsb + 224 * U5);      // 36 MB [9][1024][1024] f32
    float* MLp   = (float*)(wsb + 296 * U5);      // 256 KB [4][8][1024][2] f32

    // attention-weight cast + X rmsnorm + zero counts (FFN weights deferred)
    fused_cast<<<NCAST + 1024, 256, 0, stream>>>(wq_down, wkv, wqc, wqr, wkc, wvc, wo,
                                                 wkr, wb, h, attn_w, X16, counts);

    // --- attention branch ---
    {
        GArgs g = {};
        g.A[0] = X16; g.lda[0] = 1024; g.K[0] = 1024;
        g.seg[0] = { c_wq,  bq_down, CQraw,  768, 0, 0,  0 };
        g.seg[1] = { c_wkv, bkv,     CKVraw, 256, 0, 12, 0 };
        g.seg[2] = { c_wkr, bkr,     KRraw,  64,  0, 16, 0 };
        g.nseg = 3;
        mgemm4<<<dim3(17, 16), 256, 0, stream>>>(g);
    }
    rmsnorm2x<<<2048, 256, 0, stream>>>(CQraw, q_norm, CQ16, 768,
                                        CKVraw, kv_norm, CKV16, 256);
    {
        GArgs g = {};
        g.A[0] = CQ16;  g.lda[0] = 768; g.K[0] = 768;
        g.A[1] = CKV16; g.lda[1] = 256; g.K[1] = 256;
        g.seg[0] = { c_wqc, bqc, QC,   1024, 0, 0,  0 };
        g.seg[1] = { c_wqr, bqr, QRr,  512,  0, 16, 0 };
        g.seg[2] = { c_wkc, bkc, KC,   1024, 0, 24, 1 };
        g.seg[3] = { c_wvc, bvc, VCb,  1024, 3, 40, 1 };
        g.nseg = 4;
        mgemm4<<<dim3(56, 16), 256, 0, stream>>>(g);
    }
    pack_all<<<1280, 256, 0, stream>>>(QC, QRr, KRraw, kr_norm, KC, VCb, fcos, fsin,
                                       Qpk, Kpk, VTp);
    // attention (z<4) + FFN-weight cast (z in [4,12)) in one launch
    attn_mfma<<<dim3(16, 8, 12), 256, 0, stream>>>(Qpk, Kpk, VTp, Opart, MLp,
                                                   sw1, sw3, sw2, ew1, ew3, ew2, wb);
    attn_combine4<<<512, 256, 0, stream>>>(Opart, MLp, ATT16);
    {
        // wo GEMM: X1 = h + ATT@wo^T, ALSO pre-fills d_out with X1 so the
        // FFN combine can RMW on top.
        GArgs g = {};
        g.A[0] = ATT16; g.lda[0] = 1024; g.K[0] = 1024;
        g.seg[0] = { c_wo, bo, X1, 1024, 1, 0, 0 };
        g.nseg = 1; g.res = h; g.dst2 = (float*)d_out;
        mgemm4<<<dim3(16, 16), 256, 0, stream>>>(g);
    }

    // --- FFN + routing ---
    rmsnorm_route<<<2048, 256, 0, stream>>>(X1, ffn_w, Y16, cent, biases,
                                            counts, lists, sE, sP, sG);
    // gated GLU (U and V in one block, writes G = silu(U)*V only)
    mega_glu<<<dim3(8, 16, 9), 256, 0, stream>>>(Y16, c_sw1, sb1, c_sw3, sb3,
                                                 c_ew1, eb1, c_ew3, eb3,
                                                 Gb, lists, counts);
    // pure down GEMM on G -> per-slot scratch (no atomics, no gather)
    mega_down<<<dim3(16, 16, 9), 256, 0, stream>>>(Gb, c_sw2, sb2, c_ew2, eb2,
                                                   Dscr, counts);
    // deterministic gate+sum into d_out (which already holds X1)
    ffn_combine<<<1024, 256, 0, stream>>>(Dscr, sE, sP, sG, (float*)d_out);
}

// Round 10
// 336.956 us; speedup vs baseline: 1.0232x; 1.0232x over previous
//
#include <hip/hip_runtime.h>

typedef unsigned short u16;
typedef __attribute__((ext_vector_type(8))) short short8;   // 8 bf16 (4 VGPRs)
typedef __attribute__((ext_vector_type(4))) float f32x4;    // 4 fp32 acc

__device__ __forceinline__ float b2f(u16 u) { return __uint_as_float(((unsigned)u) << 16); }
__device__ __forceinline__ u16 f2b(float f) {
    unsigned x = __float_as_uint(f);
    return (u16)((x + 0x7fffu + ((x >> 16) & 1u)) >> 16);
}

// async global->LDS, 16B per lane; LDS dest = wave-uniform base + lane*16
#define GLDS16(gp, lp) __builtin_amdgcn_global_load_lds( \
    (const __attribute__((address_space(1))) void*)(gp), \
    (__attribute__((address_space(3))) void*)(lp), 16, 0, 0)

// counted vmcnt wait (T4): leave N loads in flight, don't drain
#define WAITV(N) do { \
    asm volatile("s_waitcnt vmcnt(" #N ")" ::: "memory"); \
    __builtin_amdgcn_sched_barrier(0); \
} while (0)

// Bank-conflict swizzle (rule #21, both-sides): LDS stays linear; the lane's
// GLOBAL column pick is permuted and the read applies the same XOR.
#define KC8_SWZ(lane) ((((lane) & 3) ^ (((lane) >> 3) & 3)) << 3)
#define RD_SWZ(fm, fq) (((fq) ^ (((fm) >> 1) & 3)) << 3)

// XCD swizzle (T1): pin all blocks sharing a weight panel (same bx) to one
// XCD so the 16x panel re-reads hit that XCD's 4MB L2 instead of LLC.
__device__ __forceinline__ void xcd_swz(int& bx, int& by) {
    if ((gridDim.x & 7) == 0 && gridDim.y == 16) {
        int lid = bx + by * gridDim.x;
        int q = lid >> 3, r = lid & 7;
        by = q & 15;
        bx = r + ((q >> 4) << 3);
    }
}

// ---------------------------------------------------------------------------
// Grouped MFMA GEMM: up to 4 column-segments, 2 A operands.
// Tile 64M x 64N, BK=32 stages, 6-buffer rotation, two stages per barrier
// (8 MFMAs/barrier), counted vmcnt (steady 4).  epi: 0 fp32; 1 fp32 += res
// (dual dst2); 3 bf16.
// gridDim.z==2 => SPLIT-K: blockIdx.z picks K-half, C offset by z*1M floats,
// bias applied on the z==0 half only (consumer sums the two partials).
// NOTE (R7 lesson): 128-row M-tile halves block count -> net -7% at these
// M=1024 shapes.  Block count is the binding constraint; keep 64x64.
// ---------------------------------------------------------------------------
struct Seg { const u16* W; const float* bias; void* C; int ldc; int epi; int bx0; int aidx; };
struct GArgs {
    const u16* A[2]; int lda[2]; int K[2];
    Seg seg[4]; int nseg;
    const float* res;
    float* dst2;
};

__launch_bounds__(256)
__global__ void mgemm4(GArgs ga)
{
    __shared__ u16 As[6 * 2048];   // 6 bufs x [64 rows][32 k] = 24 KB
    __shared__ u16 Bs[6 * 2048];
    int bx = blockIdx.x, by = blockIdx.y;
    xcd_swz(bx, by);
    int si = 0;
#pragma unroll
    for (int i = 1; i < 4; i++)
        if (i < ga.nseg && bx >= ga.seg[i].bx0) si = i;
    const u16* Wp = ga.seg[si].W;
    const float* bp = ga.seg[si].bias;
    void* Cp = ga.seg[si].C;
    const int ldco = ga.seg[si].ldc;
    const int epi = ga.seg[si].epi;
    const int ai = ga.seg[si].aidx;
    const u16* Ap = ga.A[ai];
    const int lda = ga.lda[ai];
    int K = ga.K[ai];
    const int col0 = (bx - ga.seg[si].bx0) * 64;
    const int row0 = by * 64;

    // split-K (wo GEMM): halve K range, offset C, zero bias on z==1
    const int kz = (gridDim.z == 2) ? blockIdx.z : 0;
    int koff = 0;
    if (gridDim.z == 2) { K >>= 1; koff = kz * K; Cp = (void*)((float*)Cp + (size_t)kz * 1048576); }

    int tid = threadIdx.x;
    int lane = tid & 63, w = tid >> 6;
    int r0 = (w << 4) + (lane >> 2), kc8 = KC8_SWZ(lane);
    const u16* gA = Ap + (size_t)(row0 + r0) * lda + kc8 + koff;
    const u16* gB = Wp + (size_t)(col0 + r0) * lda + kc8 + koff;   // ldw == lda

    int fm = lane & 15, fq = lane >> 4;
    const int so = RD_SWZ(fm, fq);
    f32x4 acc[4] = {};

#define MG_STAGE(BS, KO) do { \
    GLDS16(gA + (KO), As + (BS) * 2048 + (w << 9)); \
    GLDS16(gB + (KO), Bs + (BS) * 2048 + (w << 9)); \
} while (0)

    const int nst = K >> 5;      // >= 8 always, even (split wo: 16)
    MG_STAGE(0, 0); MG_STAGE(1, 32); MG_STAGE(2, 64); MG_STAGE(3, 96);
    int bcur = 0;
    for (int t = 0; t < nst; t += 2) {
        if (t < nst - 2) { WAITV(4); } else { WAITV(0); }
        __builtin_amdgcn_s_barrier();
        int w4 = bcur + 4; if (w4 >= 6) w4 -= 6;
        int w5 = w4 + 1;   if (w5 >= 6) w5 -= 6;
        if (t + 4 < nst) MG_STAGE(w4, (t + 4) << 5);
        if (t + 5 < nst) MG_STAGE(w5, (t + 5) << 5);
#pragma unroll
        for (int sub = 0; sub < 2; sub++) {
            int bc = bcur + sub; if (bc >= 6) bc -= 6;
            short8 af = *(const short8*)(As + bc * 2048 + (w << 9) + fm * 32 + so);
            short8 bf[4];
#pragma unroll
            for (int nt = 0; nt < 4; nt++)
                bf[nt] = *(const short8*)(Bs + bc * 2048 + ((nt << 4) + fm) * 32 + so);
#pragma unroll
            for (int nt = 0; nt < 4; nt++)
                acc[nt] = __builtin_amdgcn_mfma_f32_16x16x32_bf16(af, bf[nt], acc[nt], 0, 0, 0);
        }
        bcur += 2; if (bcur >= 6) bcur -= 6;
    }
#undef MG_STAGE

    // C/D layout: col = lane&15, row = (lane>>4)*4 + reg   [m89/m91]
    int rbase = row0 + (w << 4) + (fq << 2);
#pragma unroll
    for (int nt = 0; nt < 4; nt++) {
        int c = col0 + (nt << 4) + fm;
        float bcol = kz ? 0.f : bp[c];
#pragma unroll
        for (int reg = 0; reg < 4; reg++) {
            int r = rbase + reg;
            float v = acc[nt][reg] + bcol;
            if (epi == 3)
                ((u16*)Cp)[(size_t)r * ldco + c] = f2b(v);
            else if (epi == 1) {
                float o = v + ga.res[(size_t)r * ldco + c];
                ((float*)Cp)[(size_t)r * ldco + c] = o;
                if (ga.dst2) ga.dst2[(size_t)r * ldco + c] = o;
            } else
                ((float*)Cp)[(size_t)r * ldco + c] = v;
        }
    }
}

// ---------------------------------------------------------------------------
// mega_glu (GATED): W1 and W3 projections in one block (shared A-tile), gate
// in the epilogue, writes G = silu(U)*V only.  6-buffer 2-stage/barrier
// pipeline (16 MFMAs/barrier), counted vmcnt (steady 6).  XCD-swizzled.
// ---------------------------------------------------------------------------
__launch_bounds__(256)
__global__ void mega_glu(const u16* __restrict__ Y16,
                         const u16* __restrict__ sw1, const float* __restrict__ sb1,
                         const u16* __restrict__ sw3, const float* __restrict__ sb3,
                         const u16* __restrict__ ew1, const float* __restrict__ eb1,
                         const u16* __restrict__ ew3, const float* __restrict__ eb3,
                         u16* __restrict__ Gb,
                         const int* __restrict__ lists, const int* __restrict__ counts)
{
    __shared__ u16 As[6 * 2048];
    __shared__ u16 B1s[6 * 2048];
    __shared__ u16 B3s[6 * 2048];
    int bx = blockIdx.x, by = blockIdx.y, z = blockIdx.z;
    xcd_swz(bx, by);
    int col0 = bx * 64;
    int cnt = 1024; const int* list = nullptr;
    const u16 *W1p, *W3p; const float *b1p, *b3p;
    if (z == 0) {
        W1p = sw1; b1p = sb1; W3p = sw3; b3p = sb3;
    } else {
        int e = z - 1; cnt = counts[e]; list = lists + (e << 10);
        W1p = ew1 + (size_t)e * 512 * 1024; b1p = eb1 + e * 512;
        W3p = ew3 + (size_t)e * 512 * 1024; b3p = eb3 + e * 512;
    }
    int row0 = by * 64;
    if (row0 >= cnt) return;
    u16* Cp = Gb + (size_t)z * 524288;

    int tid = threadIdx.x, lane = tid & 63, w = tid >> 6;
    int r0 = (w << 4) + (lane >> 2), kc8 = KC8_SWZ(lane);
    int ar = row0 + r0;
    if (z > 0) ar = list[ar < cnt ? ar : cnt - 1];
    const u16* gA = Y16 + (size_t)ar * 1024 + kc8;
    const u16* gB1 = W1p + (size_t)(col0 + r0) * 1024 + kc8;
    const u16* gB3 = W3p + (size_t)(col0 + r0) * 1024 + kc8;

    int fm = lane & 15, fq = lane >> 4;
    const int so = RD_SWZ(fm, fq);
    f32x4 accU[4] = {}, accV[4] = {};

#define GL_STAGE(BS, KO) do { \
    GLDS16(gA + (KO),  As  + (BS) * 2048 + (w << 9)); \
    GLDS16(gB1 + (KO), B1s + (BS) * 2048 + (w << 9)); \
    GLDS16(gB3 + (KO), B3s + (BS) * 2048 + (w << 9)); \
} while (0)

    GL_STAGE(0, 0); GL_STAGE(1, 32); GL_STAGE(2, 64); GL_STAGE(3, 96);
    int bcur = 0;
    for (int t = 0; t < 32; t += 2) {
        if (t < 30) { WAITV(6); } else { WAITV(0); }
        __builtin_amdgcn_s_barrier();
        int w4 = bcur + 4; if (w4 >= 6) w4 -= 6;
        int w5 = w4 + 1;   if (w5 >= 6) w5 -= 6;
        if (t + 4 < 32) GL_STAGE(w4, (t + 4) << 5);
        if (t + 5 < 32) GL_STAGE(w5, (t + 5) << 5);
#pragma unroll
        for (int sub = 0; sub < 2; sub++) {
            int bc = bcur + sub; if (bc >= 6) bc -= 6;
            short8 af = *(const short8*)(As + bc * 2048 + (w << 9) + fm * 32 + so);
#pragma unroll
            for (int nt = 0; nt < 4; nt++) {
                short8 b1 = *(const short8*)(B1s + bc * 2048 + ((nt << 4) + fm) * 32 + so);
                accU[nt] = __builtin_amdgcn_mfma_f32_16x16x32_bf16(af, b1, accU[nt], 0, 0, 0);
            }
#pragma unroll
            for (int nt = 0; nt < 4; nt++) {
                short8 b3 = *(const short8*)(B3s + bc * 2048 + ((nt << 4) + fm) * 32 + so);
                accV[nt] = __builtin_amdgcn_mfma_f32_16x16x32_bf16(af, b3, accV[nt], 0, 0, 0);
            }
        }
        bcur += 2; if (bcur >= 6) bcur -= 6;
    }
#undef GL_STAGE

    int rbase = row0 + (w << 4) + (fq << 2);
#pragma unroll
    for (int nt = 0; nt < 4; nt++) {
        int c = col0 + (nt << 4) + fm;
        float b1c = b1p[c], b3c = b3p[c];
#pragma unroll
        for (int reg = 0; reg < 4; reg++) {
            int r = rbase + reg;
            if (r >= cnt) continue;
            float u = b2f(f2b(accU[nt][reg] + b1c));   // bf16 round-trip:
            float v = b2f(f2b(accV[nt][reg] + b3c));   // bit-identical to old
            Cp[(size_t)r * 512 + c] = f2b(u / (1.f + __expf(-u)) * v);
        }
    }
}

// ---------------------------------------------------------------------------
// mega_down: Dscr[z] = G[z] @ W2^T + b2.  Pure GEMM, NO atomics, NO gather
// (scratch is position-indexed; ffn_combine applies gates and sums).
// 6-buffer 2-stage/barrier pipeline.  XCD-swizzled.
// ---------------------------------------------------------------------------
__launch_bounds__(256)
__global__ void mega_down(const u16* __restrict__ Gb,
                          const u16* __restrict__ sw2, const float* __restrict__ sb2,
                          const u16* __restrict__ ew2, const float* __restrict__ eb2,
                          float* __restrict__ Dscr,
                          const int* __restrict__ counts)
{
    __shared__ u16 Gs[6 * 2048];
    __shared__ u16 Ws[6 * 2048];
    int bx = blockIdx.x, by = blockIdx.y, z = blockIdx.z;
    xcd_swz(bx, by);
    int cnt = 1024;
    const u16* Wp; const float* bp;
    if (z == 0) { Wp = sw2; bp = sb2; }
    else {
        int e = z - 1;
        cnt = counts[e];
        Wp = ew2 + (size_t)e * 1024 * 512; bp = eb2 + e * 1024;
    }
    int row0 = by * 64;
    if (row0 >= cnt) return;
    const u16* Ap = Gb + (size_t)z * 524288;
    int col0 = bx * 64;
    float* Dp = Dscr + (size_t)z * 1048576;

    int tid = threadIdx.x, lane = tid & 63, w = tid >> 6;
    int r0 = (w << 4) + (lane >> 2), kc8 = KC8_SWZ(lane);
    const u16* gG = Ap + (size_t)(row0 + r0) * 512 + kc8;
    const u16* gW = Wp + (size_t)(col0 + r0) * 512 + kc8;

    int fm = lane & 15, fq = lane >> 4;
    const int so = RD_SWZ(fm, fq);
    f32x4 acc[4] = {};

#define MD_STAGE(BS, KO) do { \
    GLDS16(gG + (KO), Gs + (BS) * 2048 + (w << 9)); \
    GLDS16(gW + (KO), Ws + (BS) * 2048 + (w << 9)); \
} while (0)

    MD_STAGE(0, 0); MD_STAGE(1, 32); MD_STAGE(2, 64); MD_STAGE(3, 96);
    int bcur = 0;
    for (int t = 0; t < 16; t += 2) {
        if (t < 14) { WAITV(4); } else { WAITV(0); }
        __builtin_amdgcn_s_barrier();
        int w4 = bcur + 4; if (w4 >= 6) w4 -= 6;
        int w5 = w4 + 1;   if (w5 >= 6) w5 -= 6;
        if (t + 4 < 16) MD_STAGE(w4, (t + 4) << 5);
        if (t + 5 < 16) MD_STAGE(w5, (t + 5) << 5);
#pragma unroll
        for (int sub = 0; sub < 2; sub++) {
            int bc = bcur + sub; if (bc >= 6) bc -= 6;
            short8 af = *(const short8*)(Gs + bc * 2048 + (w << 9) + fm * 32 + so);
            short8 bf[4];
#pragma unroll
            for (int nt = 0; nt < 4; nt++)
                bf[nt] = *(const short8*)(Ws + bc * 2048 + ((nt << 4) + fm) * 32 + so);
#pragma unroll
            for (int nt = 0; nt < 4; nt++)
                acc[nt] = __builtin_amdgcn_mfma_f32_16x16x32_bf16(af, bf[nt], acc[nt], 0, 0, 0);
        }
        bcur += 2; if (bcur >= 6) bcur -= 6;
    }
#undef MD_STAGE

    int rbase = row0 + (w << 4) + (fq << 2);
#pragma unroll
    for (int nt = 0; nt < 4; nt++) {
        int c = col0 + (nt << 4) + fm;
        float bcol = bp[c];
#pragma unroll
        for (int reg = 0; reg < 4; reg++) {
            int r = rbase + reg;   // rows >= cnt: garbage, never read
            Dp[(size_t)r * 1024 + c] = acc[nt][reg] + bcol;
        }
    }
}

// ffn combine: out[t] += Dsh[t] + g0*De[e0][p0] + g1*De[e1][p1].  1024 blocks.
__launch_bounds__(256)
__global__ void ffn_combine(const float* __restrict__ Dscr,
                            const int* __restrict__ sE, const int* __restrict__ sP,
                            const float* __restrict__ sG,
                            float* __restrict__ out)
{
    int t = blockIdx.x, tid = threadIdx.x;
    int e0 = sE[t * 2], e1 = sE[t * 2 + 1];
    int p0 = sP[t * 2], p1 = sP[t * 2 + 1];
    float g0 = sG[t * 2], g1 = sG[t * 2 + 1];
    const float4* Ds = (const float4*)(Dscr + (size_t)t * 1024);
    const float4* D0 = (const float4*)(Dscr + (size_t)(e0 + 1) * 1048576 + (size_t)p0 * 1024);
    const float4* D1 = (const float4*)(Dscr + (size_t)(e1 + 1) * 1048576 + (size_t)p1 * 1024);
    float4* o = (float4*)(out + (size_t)t * 1024);
    float4 a = o[tid], s = Ds[tid], x0 = D0[tid], x1 = D1[tid];
    a.x += s.x + g0 * x0.x + g1 * x1.x;
    a.y += s.y + g0 * x0.y + g1 * x1.y;
    a.z += s.z + g0 * x0.z + g1 * x1.z;
    a.w += s.w + g0 * x0.w + g1 * x1.w;
    o[tid] = a;
}

// ---------------------------------------------------------------------------
// MFMA flash attention, 64-wide K-tiles, 4-way KV-SPLIT over blockIdx.z
// (z in [0,4)), PLUS FFN-weight cast blocks (z in [4,12)).  Each attention
// z-chunk writes unnormalized fp32 O + (m,l); attn_combine4 merges exactly.
// ---------------------------------------------------------------------------
__launch_bounds__(256)
__global__ void attn_mfma(const u16* __restrict__ Qp, const u16* __restrict__ Kp,
                          const u16* __restrict__ VT,
                          float* __restrict__ Opart, float* __restrict__ MLp,
                          const float* __restrict__ fsw1, const float* __restrict__ fsw3,
                          const float* __restrict__ fsw2, const float* __restrict__ few1,
                          const float* __restrict__ few3, const float* __restrict__ few2,
                          u16* __restrict__ warena)
{
    const int qt = blockIdx.x, h = blockIdx.y, z = blockIdx.z;
    if (z >= 4) {
        // ---- FFN weight cast: arena range [3801088, 17956864) ----
        int cb = (z - 4) * 128 + h * 16 + qt;        // 0..1023
        const int NQ4 = (17956864 - 3801088) / 4;    // 3538944 float4s
        for (int i = cb * 256 + threadIdx.x; i < NQ4; i += 1024 * 256) {
            int e = 3801088 + i * 4;
            const float* s; int base;
            if      (e <  4325376) { s = fsw1; base =  3801088; }
            else if (e <  4849664) { s = fsw3; base =  4325376; }
            else if (e <  5373952) { s = fsw2; base =  4849664; }
            else if (e <  9568256) { s = few1; base =  5373952; }
            else if (e < 13762560) { s = few3; base =  9568256; }
            else                   { s = few2; base = 13762560; }
            float4 v = *(const float4*)(s + (e - base));
            ushort4 o;
            o.x = f2b(v.x); o.y = f2b(v.y); o.z = f2b(v.z); o.w = f2b(v.w);
            *(ushort4*)(warena + e) = o;
        }
        return;
    }
    const int q0 = qt * 64;
    const int tid = threadIdx.x;
    const int lane = tid & 63, w = tid >> 6;
    const int fm = lane & 15, fq = lane >> 4;

    __shared__ u16 Ks[12288];   // 6 chunks x [64 kv][32 k]  (24 KB)
    __shared__ u16 Vs[8192];    // 2 kc x [128 d][32 kv]     (16 KB)
    __shared__ u16 Ps[4096];    // per wave: [2 kc][16 m][32 kv] (8 KB)

    const u16* qrow = Qp + ((size_t)h * 1024 + q0 + w * 16 + fm) * 192;
    short8 qf[6];
#pragma unroll
    for (int c = 0; c < 6; c++)
        qf[c] = *(const short8*)(qrow + c * 32 + fq * 8);

    const u16* Kb = Kp + (size_t)h * 1024 * 192;
    const u16* Vb = VT + (size_t)h * 128 * 1024;

    float m_i[4], l_i[4];
#pragma unroll
    for (int r = 0; r < 4; r++) { m_i[r] = -1e30f; l_i[r] = 0.f; }
    f32x4 accO[8] = {};
    const float scale = 0.07216878364870323f;  // 1/sqrt(192)
    const int nt64 = qt + 1;                   // 64-wide tiles needed
    const int ktlo = (z * nt64) >> 2;
    const int kthi = ((z + 1) * nt64) >> 2;
    const int rbase = w * 16 + fq * 4;

    for (int kt = ktlo; kt < kthi; ++kt) {
        const int o = kt * 64;
#pragma unroll
        for (int i = 0; i < 6; i++) {
            int idx = w + 4 * i;                 // 0..23
            int c = idx >> 2, k4 = idx & 3;
            const u16* g = Kb + (size_t)(o + k4 * 16 + (lane >> 2)) * 192 + c * 32 + (lane & 3) * 8;
            GLDS16(g, Ks + c * 2048 + k4 * 512 + lane * 8);
        }
#pragma unroll
        for (int i = 0; i < 4; i++) {
            int idx = w + 4 * i;                 // 0..15
            int kc = idx >> 3, k8 = idx & 7;
            const u16* g = Vb + (size_t)(k8 * 16 + (lane >> 2)) * 1024 + o + kc * 32 + (lane & 3) * 8;
            GLDS16(g, Vs + kc * 4096 + k8 * 512 + lane * 8);
        }
        __syncthreads();
        // ---- S = Q K^T (24 MFMAs over 64 cols) ----
        f32x4 sacc[4];
        __builtin_amdgcn_s_setprio(1);
#pragma unroll
        for (int nt = 0; nt < 4; nt++) {
            sacc[nt] = (f32x4){0.f, 0.f, 0.f, 0.f};
#pragma unroll
            for (int c = 0; c < 6; c++) {
                short8 kf = *(const short8*)(Ks + c * 2048 + (nt * 16 + fm) * 32 + fq * 8);
                sacc[nt] = __builtin_amdgcn_mfma_f32_16x16x32_bf16(qf[c], kf, sacc[nt], 0, 0, 0);
            }
        }
        __builtin_amdgcn_s_setprio(0);
        // ---- online softmax (mask: global col index > q row) ----
        float pv[4][4], rmax[4];
#pragma unroll
        for (int reg = 0; reg < 4; reg++) {
            int q = q0 + rbase + reg;
            float mx = -1e30f;
#pragma unroll
            for (int nt = 0; nt < 4; nt++) {
                int gk = o + nt * 16 + fm;
                float s = sacc[nt][reg] * scale;
                if (gk > q) s = -1e30f;
                pv[nt][reg] = s;
                mx = fmaxf(mx, s);
            }
            rmax[reg] = mx;
        }
#pragma unroll
        for (int m = 1; m < 16; m <<= 1)
#pragma unroll
            for (int reg = 0; reg < 4; reg++)
                rmax[reg] = fmaxf(rmax[reg], __shfl_xor(rmax[reg], m));
        float alpha[4], rsum[4];
#pragma unroll
        for (int reg = 0; reg < 4; reg++) {
            float mn = fmaxf(m_i[reg], rmax[reg]);
            alpha[reg] = __expf(m_i[reg] - mn);
            m_i[reg] = mn;
            float s = 0.f;
#pragma unroll
            for (int nt = 0; nt < 4; nt++) {
                float p = __expf(pv[nt][reg] - mn);
                pv[nt][reg] = p;
                s += p;
            }
            rsum[reg] = s;
        }
#pragma unroll
        for (int m = 1; m < 16; m <<= 1)
#pragma unroll
            for (int reg = 0; reg < 4; reg++)
                rsum[reg] += __shfl_xor(rsum[reg], m);
#pragma unroll
        for (int reg = 0; reg < 4; reg++)
            l_i[reg] = l_i[reg] * alpha[reg] + rsum[reg];
        // ---- P (C-layout) -> LDS (A-layout, bf16); per-wave slice ----
#pragma unroll
        for (int nt = 0; nt < 4; nt++)
#pragma unroll
            for (int reg = 0; reg < 4; reg++)
                Ps[w * 1024 + (nt >> 1) * 512 + (fq * 4 + reg) * 32 + (nt & 1) * 16 + fm]
                    = f2b(pv[nt][reg]);
        // ---- rescale O, then O += P V (16 MFMAs) ----
#pragma unroll
        for (int n2 = 0; n2 < 8; n2++)
#pragma unroll
            for (int reg = 0; reg < 4; reg++)
                accO[n2][reg] *= alpha[reg];
        short8 pf[2];
#pragma unroll
        for (int kc = 0; kc < 2; kc++)
            pf[kc] = *(const short8*)(Ps + w * 1024 + kc * 512 + fm * 32 + fq * 8);
        __builtin_amdgcn_s_setprio(1);
#pragma unroll
        for (int n2 = 0; n2 < 8; n2++)
#pragma unroll
            for (int kc = 0; kc < 2; kc++) {
                short8 vf = *(const short8*)(Vs + kc * 4096 + (n2 * 16 + fm) * 32 + fq * 8);
                accO[n2] = __builtin_amdgcn_mfma_f32_16x16x32_bf16(pf[kc], vf, accO[n2], 0, 0, 0);
            }
        __builtin_amdgcn_s_setprio(0);
        __syncthreads();
    }
    // ---- write unnormalized partial O (fp32) + (m,l) ----
    float* Ob = Opart + ((size_t)(z * 8 + h) * 1024) * 128;
#pragma unroll
    for (int reg = 0; reg < 4; reg++) {
        int row = q0 + rbase + reg;
#pragma unroll
        for (int n2 = 0; n2 < 8; n2++)
            Ob[(size_t)row * 128 + n2 * 16 + fm] = accO[n2][reg];
        if (fm == 0) {
            MLp[((size_t)(z * 8 + h) * 1024 + row) * 2]     = m_i[reg];
            MLp[((size_t)(z * 8 + h) * 1024 + row) * 2 + 1] = l_i[reg];
        }
    }
}

// exact online-softmax merge of the four KV-split partials -> bf16 ATT16
__launch_bounds__(256)
__global__ void attn_combine4(const float* __restrict__ Opart,
                              const float* __restrict__ MLp,
                              u16* __restrict__ O)
{
    int tid = threadIdx.x;
    int rowg = blockIdx.x * 16 + (tid >> 4);        // 0..8191 = h*1024+row
    int h = rowg >> 10, row = rowg & 1023;
    int c0 = (tid & 15) * 8;
    float m[4], l[4];
    float M = -1e30f;
#pragma unroll
    for (int z = 0; z < 4; z++) {
        m[z] = MLp[((size_t)(z * 8 + h) * 1024 + row) * 2];
        l[z] = MLp[((size_t)(z * 8 + h) * 1024 + row) * 2 + 1];
        M = fmaxf(M, m[z]);
    }
    float wz[4], den = 0.f;
#pragma unroll
    for (int z = 0; z < 4; z++) { wz[z] = __expf(m[z] - M); den += l[z] * wz[z]; }
    float inv = 1.f / den;
#pragma unroll
    for (int j = 0; j < 8; j++) {
        float o = 0.f;
#pragma unroll
        for (int z = 0; z < 4; z++)
            o += Opart[((size_t)(z * 8 + h) * 1024 + row) * 128 + c0 + j] * wz[z];
        O[(size_t)row * 1024 + h * 128 + c0 + j] = f2b(o * inv);
    }
}

// two rmsnorms (bf16 out) in one launch
__launch_bounds__(256)
__global__ void rmsnorm2x(const float* __restrict__ X0, const float* __restrict__ w0,
                          u16* __restrict__ O0, int c0,
                          const float* __restrict__ X1, const float* __restrict__ w1,
                          u16* __restrict__ O1, int c1)
{
    int b = blockIdx.x, tid = threadIdx.x;
    const float* X; const float* w; u16* O; int cols; int r;
    if (b < 1024) { X = X0; w = w0; O = O0; cols = c0; r = b; }
    else          { X = X1; w = w1; O = O1; cols = c1; r = b - 1024; }
    const float* xr = X + (size_t)r * cols;
    float ss = 0.f;
    for (int j = tid; j < cols; j += 256) { float v = xr[j]; ss += v * v; }
    __shared__ float red[256];
    red[tid] = ss; __syncthreads();
    for (int st = 128; st > 0; st >>= 1) { if (tid < st) red[tid] += red[tid + st]; __syncthreads(); }
    float scale = rsqrtf(red[0] / cols + 1e-6f);
    for (int j = tid; j < cols; j += 256)
        O[(size_t)r * cols + j] = f2b(xr[j] * scale * w[j]);
}

// ---------------------------------------------------------------------------
// rmsnorm_route: X1 = h + P0 + P1 computed ON THE FLY from the wo split-K
// partials (and written to d_out once).  Blocks [0,1024): Y16 =
// bf16(rmsnorm(X1,ffn_w)) + d_out write; blocks [1024,2048): routing.
// ---------------------------------------------------------------------------
__launch_bounds__(256)
__global__ void rmsnorm_route(const float* __restrict__ hres,
                              const float* __restrict__ P0, const float* __restrict__ P1,
                              const float* __restrict__ ffnw,
                              u16* __restrict__ Y16, float* __restrict__ dout,
                              const float* __restrict__ cent, const float* __restrict__ biases,
                              int* __restrict__ counts, int* __restrict__ lists,
                              int* __restrict__ sE, int* __restrict__ sP,
                              float* __restrict__ sG)
{
    __shared__ float red[256];
    int b = blockIdx.x, tid = threadIdx.x;
    if (b < 1024) {
        int r = b;
        size_t base = (size_t)r * 1024;
        float ss = 0.f;
        for (int j = tid; j < 1024; j += 256) {
            float x1 = hres[base + j] + P0[base + j] + P1[base + j];
            dout[base + j] = x1;
            ss += x1 * x1;
        }
        red[tid] = ss; __syncthreads();
        for (int st = 128; st > 0; st >>= 1) { if (tid < st) red[tid] += red[tid + st]; __syncthreads(); }
        float scale = rsqrtf(red[0] / 1024.f + 1e-6f);
        for (int j = tid; j < 1024; j += 256)
            Y16[base + j] = f2b(dout[base + j] * scale * ffnw[j]);
    } else {
        int t = b - 1024;
        size_t base = (size_t)t * 1024;
        float ss = 0.f;
        float acc[8] = {};
        for (int j = tid; j < 1024; j += 256) {
            float x = hres[base + j] + P0[base + j] + P1[base + j];
            ss += x * x;
            float yp = x * ffnw[j];
#pragma unroll
            for (int e = 0; e < 8; e++) acc[e] += yp * cent[e * 1024 + j];
        }
        red[tid] = ss; __syncthreads();
        for (int st = 128; st > 0; st >>= 1) { if (tid < st) red[tid] += red[tid + st]; __syncthreads(); }
        float scale = rsqrtf(red[0] / 1024.f + 1e-6f);
        __syncthreads();
        __shared__ float aff[8];
        for (int e = 0; e < 8; e++) {
            red[tid] = acc[e]; __syncthreads();
            for (int st = 128; st > 0; st >>= 1) { if (tid < st) red[tid] += red[tid + st]; __syncthreads(); }
            if (tid == 0) aff[e] = 1.f / (1.f + expf(-red[0] * scale));
            __syncthreads();
        }
        if (tid == 0) {
            float sb[8];
#pragma unroll
            for (int e = 0; e < 8; e++) sb[e] = aff[e] + biases[e];
            int i0 = 0;
            for (int e = 1; e < 8; e++) if (sb[e] > sb[i0]) i0 = e;
            int i1 = -1;
            for (int e = 0; e < 8; e++) { if (e == i0) continue; if (i1 < 0 || sb[e] > sb[i1]) i1 = e; }
            float a0 = aff[i0], a1 = aff[i1];
            float mx = fmaxf(a0, a1);
            float e0 = expf(a0 - mx), e1 = expf(a1 - mx);
            float inv = 1.f / (e0 + e1);
            int p0 = atomicAdd(&counts[i0], 1);
            lists[i0 * 1024 + p0] = t;
            int p1 = atomicAdd(&counts[i1], 1);
            lists[i1 * 1024 + p1] = t;
            sE[t * 2] = i0; sP[t * 2] = p0; sG[t * 2] = e0 * inv;
            sE[t * 2 + 1] = i1; sP[t * 2 + 1] = p1; sG[t * 2 + 1] = e1 * inv;
        }
    }
}

// ---------------------------------------------------------------------------
// pack_all: blocks [0,1024): KR rmsnorm+rope, pack Q (QR rope) and K.
// Blocks [1024,1280): transpose V (bf16 [s][d] -> [d][s]).
// ---------------------------------------------------------------------------
__launch_bounds__(256)
__global__ void pack_all(const float* __restrict__ QC, const float* __restrict__ QRr,
                         const float* __restrict__ KRraw, const float* __restrict__ krw,
                         const float* __restrict__ KC,
                         const u16* __restrict__ VCb,
                         const float* __restrict__ fcos, const float* __restrict__ fsin,
                         u16* __restrict__ Qp, u16* __restrict__ Kp, u16* __restrict__ VT)
{
    __shared__ u16 Ts[64][68];
    __shared__ float kshared[64];
    int b = blockIdx.x, tid = threadIdx.x;
    if (b < 1024) {
        int s = b;
        if (tid < 64) {
            float v = KRraw[(size_t)s * 64 + tid];
            float ss = v * v;
#pragma unroll
            for (int m = 1; m < 64; m <<= 1) ss += __shfl_xor(ss, m);
            float scale = rsqrtf(ss / 64.f + 1e-6f);
            int j = tid >> 1;
            float c = fcos[s * 32 + j], sn = fsin[s * 32 + j];
            float x0 = KRraw[(size_t)s * 64 + (tid & ~1)] * scale * krw[tid & ~1];
            float x1 = KRraw[(size_t)s * 64 + (tid | 1)]  * scale * krw[tid | 1];
            kshared[tid] = (tid & 1) ? (x0 * sn + x1 * c) : (x0 * c - x1 * sn);
        }
        __syncthreads();
        for (int e = tid; e < 1536; e += 256) {
            int h = e / 192, d = e % 192;
            float q;
            if (d < 128) {
                q = QC[(size_t)s * 1024 + h * 128 + d];
            } else {
                int dd = d - 128, j = dd >> 1;
                float c = fcos[s * 32 + j], sn = fsin[s * 32 + j];
                float x0 = QRr[(size_t)s * 512 + h * 64 + (dd & ~1)];
                float x1 = QRr[(size_t)s * 512 + h * 64 + (dd | 1)];
                q = (dd & 1) ? (x0 * sn + x1 * c) : (x0 * c - x1 * sn);
            }
            Qp[((size_t)h * 1024 + s) * 192 + d] = f2b(q);
            float k = (d < 64) ? kshared[d]
                               : KC[(size_t)s * 1024 + h * 128 + d - 64];
            Kp[((size_t)h * 1024 + s) * 192 + d] = f2b(k);
        }
    } else {
        int idx = b - 1024;
        int s0 = (idx & 15) * 64, d0 = (idx >> 4) * 64;
        for (int k = 0; k < 16; k++) {
            int e = tid + k * 256, r = e >> 6, c = e & 63;
            Ts[r][c] = VCb[(size_t)(s0 + r) * 1024 + d0 + c];
        }
        __syncthreads();
        for (int k = 0; k < 16; k++) {
            int e = tid + k * 256, d = e >> 6, s = e & 63;
            VT[(size_t)(d0 + d) * 1024 + s0 + s] = Ts[s][d];
        }
    }
}

// ---------------------------------------------------------------------------
// fused_cast (ATTENTION-ONLY): fp32->bf16 cast of the attention-path weights
// (wq,wkv,wqc,wqr,wkc,wvc,wo + wkr at arena tail) + the X rmsnorm (blocks >=
// NCAST) + zeroing of counts[8].  FFN weights are cast inside the attn_mfma
// launch.
// ---------------------------------------------------------------------------
#define NCAST 1024
__launch_bounds__(256)
__global__ void fused_cast(const float* p0, const float* p1, const float* p2,
                           const float* p3, const float* p4, const float* p5,
                           const float* p6, const float* pkr,
                           u16* __restrict__ dst,
                           const float* __restrict__ hX, const float* __restrict__ attnw,
                           u16* __restrict__ X16, int* __restrict__ zc)
{
    __shared__ float red[256];
    int b = blockIdx.x, tid = threadIdx.x;
    if (b < NCAST) {
        const int NQ = 3866624 / 4;    // 3801088 attn weights + 65536 wkr
        for (int i = b * 256 + tid; i < NQ; i += NCAST * 256) {
            int e = i * 4;
            const float* s; int base; int dstoff;
            if      (e <   786432) { s = p0;  base = 0;       dstoff = e; }
            else if (e <  1048576) { s = p1;  base =  786432; dstoff = e; }
            else if (e <  1835008) { s = p2;  base = 1048576; dstoff = e; }
            else if (e <  2228224) { s = p3;  base = 1835008; dstoff = e; }
            else if (e <  2490368) { s = p4;  base = 2228224; dstoff = e; }
            else if (e <  2752512) { s = p5;  base = 2490368; dstoff = e; }
            else if (e <  3801088) { s = p6;  base = 2752512; dstoff = e; }
            else { s = pkr; base = 3801088; dstoff = 17956864 + (e - 3801088); }
            float4 v = *(const float4*)(s + (e - base));
            ushort4 o;
            o.x = f2b(v.x); o.y = f2b(v.y); o.z = f2b(v.z); o.w = f2b(v.w);
            *(ushort4*)(dst + dstoff) = o;
        }
    } else {
        int r = b - NCAST;
        if (r == 0 && tid < 8) zc[tid] = 0;   // counts[8]
        const float* xr = hX + (size_t)r * 1024;
        float ss = 0.f;
        for (int j = tid; j < 1024; j += 256) { float v = xr[j]; ss += v * v; }
        red[tid] = ss; __syncthreads();
        for (int st = 128; st > 0; st >>= 1) { if (tid < st) red[tid] += red[tid + st]; __syncthreads(); }
        float scale = rsqrtf(red[0] / 1024.f + 1e-6f);
        for (int j = tid; j < 1024; j += 256)
            X16[(size_t)r * 1024 + j] = f2b(xr[j] * scale * attnw[j]);
    }
}

// ---------------------------------------------------------------------------
extern "C" void kernel_launch(void* const* d_in, const int* in_sizes, int n_in,
                              void* d_out, int out_size, void* d_ws, size_t ws_size,
                              hipStream_t stream)
{
    (void)in_sizes; (void)n_in; (void)ws_size; (void)out_size;
    const float* h       = (const float*)d_in[0];
    const float* fcos    = (const float*)d_in[1];
    const float* fsin    = (const float*)d_in[2];
    const float* attn_w  = (const float*)d_in[4];
    const float* ffn_w   = (const float*)d_in[5];
    const float* wq_down = (const float*)d_in[6];
    const float* bq_down = (const float*)d_in[7];
    const float* q_norm  = (const float*)d_in[8];
    const float* wqc     = (const float*)d_in[9];
    const float* bqc     = (const float*)d_in[10];
    const float* wqr     = (const float*)d_in[11];
    const float* bqr     = (const float*)d_in[12];
    const float* wkr     = (const float*)d_in[13];
    const float* bkr     = (const float*)d_in[14];
    const float* kr_norm = (const float*)d_in[15];
    const float* wkv     = (const float*)d_in[16];
    const float* bkv     = (const float*)d_in[17];
    const float* kv_norm = (const float*)d_in[18];
    const float* wkc     = (const float*)d_in[19];
    const float* bkc     = (const float*)d_in[20];
    const float* wvc     = (const float*)d_in[21];
    const float* bvc     = (const float*)d_in[22];
    const float* wo      = (const float*)d_in[23];
    const float* bo      = (const float*)d_in[24];
    const float* sw1     = (const float*)d_in[25];
    const float* sb1     = (const float*)d_in[26];
    const float* sw2     = (const float*)d_in[27];
    const float* sb2     = (const float*)d_in[28];
    const float* sw3     = (const float*)d_in[29];
    const float* sb3     = (const float*)d_in[30];
    const float* ew1     = (const float*)d_in[31];
    const float* eb1     = (const float*)d_in[32];
    const float* ew2     = (const float*)d_in[33];
    const float* eb2     = (const float*)d_in[34];
    const float* ew3     = (const float*)d_in[35];
    const float* eb3     = (const float*)d_in[36];
    const float* cent    = (const float*)d_in[37];
    const float* biases  = (const float*)d_in[38];

    char* wsb = (char*)d_ws;
    const size_t U5 = 512 * 1024;  // 0.5 MB unit
    u16*   X16   = (u16*)(wsb + 8 * U5);       // 2 MB
    float* QRr   = (float*)(wsb + 12 * U5);    // 2 MB
    float* CQraw = (float*)(wsb + 16 * U5);    // 3 MB (early)
    u16*   ATT16 = (u16*)(wsb + 16 * U5);      // 2 MB (after CQraw dead)
    u16*   CQ16  = (u16*)(wsb + 22 * U5);      // 1.5 MB
    float* CKVraw= (float*)(wsb + 25 * U5);    // 1 MB
    u16*   CKV16 = (u16*)(wsb + 27 * U5);      // 0.5 MB
    float* KRraw = (float*)(wsb + 28 * U5);    // 0.25 MB
    float* QC    = (float*)(wsb + 29 * U5);    // 4 MB (dead after pack)
    float* KC    = (float*)(wsb + 37 * U5);    // 4 MB (dead after pack)
    int*   counts= (int*)(wsb + 61 * U5 + 64 * 1024);
    int*   lists = (int*)(wsb + 61 * U5 + 32 * 1024);
    int*   sE    = (int*)(wsb + 61 * U5 + 72 * 1024);   // 8 KB
    int*   sP    = (int*)(wsb + 61 * U5 + 80 * 1024);   // 8 KB
    float* sG    = (float*)(wsb + 61 * U5 + 88 * 1024); // 8 KB
    u16*   Y16   = (u16*)(wsb + 69 * U5);      // 2 MB
    u16*   Gb    = (u16*)(wsb + 73 * U5);      // 9 MB gated GLU output (73..90)

    // bf16 weight arena (contiguous; attn block [0,3801088), FFN block
    // [3801088,17956864), wkr tail [17956864,18022400))
    u16* wb = (u16*)(wsb + 92 * U5);
    u16 *c_wq  = wb;
    u16 *c_wkv = c_wq  + 786432;
    u16 *c_wqc = c_wkv + 262144;
    u16 *c_wqr = c_wqc + 786432;
    u16 *c_wkc = c_wqr + 393216;
    u16 *c_wvc = c_wkc + 262144;
    u16 *c_wo  = c_wvc + 262144;
    u16 *c_sw1 = c_wo  + 1048576;
    u16 *c_sw3 = c_sw1 + 524288;
    u16 *c_sw2 = c_sw3 + 524288;
    u16 *c_ew1 = c_sw2 + 524288;
    u16 *c_ew3 = c_ew1 + 4194304;
    u16 *c_ew2 = c_ew3 + 4194304;
    u16 *c_wkr = c_ew2 + 4194304;                 // 64x1024 (exact)
    u16* VCb = (u16*)(wsb + 92 * U5 + 36175872);  // 2 MB bf16 V [s][d]
    u16* VTp = VCb + 1048576;                     // 2 MB bf16 V^T [d][s]
    u16* Qpk = VTp + 1048576;                     // 3 MB
    u16* Kpk = Qpk + 1572864;                     // 3 MB
    // scratch (ws ~268 MB)
    float* Opart = (float*)(wsb + 192 * U5);      // 16 MB [4][8][1024][128] f32
                                                  // reused as wo split-K P0/P1
    float* Dscr  = (float*)(wsb + 224 * U5);      // 36 MB [9][1024][1024] f32
    float* MLp   = (float*)(wsb + 296 * U5);      // 256 KB [4][8][1024][2] f32

    // attention-weight cast + X rmsnorm + zero counts (FFN weights deferred)
    fused_cast<<<NCAST + 1024, 256, 0, stream>>>(wq_down, wkv, wqc, wqr, wkc, wvc, wo,
                                                 wkr, wb, h, attn_w, X16, counts);

    // --- attention branch ---
    {
        GArgs g = {};
        g.A[0] = X16; g.lda[0] = 1024; g.K[0] = 1024;
        g.seg[0] = { c_wq,  bq_down, CQraw,  768, 0, 0,  0 };
        g.seg[1] = { c_wkv, bkv,     CKVraw, 256, 0, 12, 0 };
        g.seg[2] = { c_wkr, bkr,     KRraw,  64,  0, 16, 0 };
        g.nseg = 3;
        mgemm4<<<dim3(17, 16), 256, 0, stream>>>(g);
    }
    rmsnorm2x<<<2048, 256, 0, stream>>>(CQraw, q_norm, CQ16, 768,
                                        CKVraw, kv_norm, CKV16, 256);
    {
        GArgs g = {};
        g.A[0] = CQ16;  g.lda[0] = 768; g.K[0] = 768;
        g.A[1] = CKV16; g.lda[1] = 256; g.K[1] = 256;
        g.seg[0] = { c_wqc, bqc, QC,   1024, 0, 0,  0 };
        g.seg[1] = { c_wqr, bqr, QRr,  512,  0, 16, 0 };
        g.seg[2] = { c_wkc, bkc, KC,   1024, 0, 24, 1 };
        g.seg[3] = { c_wvc, bvc, VCb,  1024, 3, 40, 1 };
        g.nseg = 4;
        mgemm4<<<dim3(56, 16), 256, 0, stream>>>(g);
    }
    pack_all<<<1280, 256, 0, stream>>>(QC, QRr, KRraw, kr_norm, KC, VCb, fcos, fsin,
                                       Qpk, Kpk, VTp);
    // attention (z<4) + FFN-weight cast (z in [4,12)) in one launch
    attn_mfma<<<dim3(16, 8, 12), 256, 0, stream>>>(Qpk, Kpk, VTp, Opart, MLp,
                                                   sw1, sw3, sw2, ew1, ew3, ew2, wb);
    attn_combine4<<<512, 256, 0, stream>>>(Opart, MLp, ATT16);
    {
        // wo GEMM, SPLIT-K x2 (512 blocks): partials P0/P1 into Opart
        // (dead after combine4); bias on the z=0 half.  rmsnorm_route
        // computes X1 = h + P0 + P1 and writes d_out.
        GArgs g = {};
        g.A[0] = ATT16; g.lda[0] = 1024; g.K[0] = 1024;
        g.seg[0] = { c_wo, bo, Opart, 1024, 0, 0, 0 };
        g.nseg = 1;
        mgemm4<<<dim3(16, 16, 2), 256, 0, stream>>>(g);
    }

    // --- FFN + routing (X1 computed on the fly from wo partials) ---
    rmsnorm_route<<<2048, 256, 0, stream>>>(h, Opart, Opart + 1048576, ffn_w,
                                            Y16, (float*)d_out, cent, biases,
                                            counts, lists, sE, sP, sG);
    // gated GLU (U and V in one block, writes G = silu(U)*V only)
    mega_glu<<<dim3(8, 16, 9), 256, 0, stream>>>(Y16, c_sw1, sb1, c_sw3, sb3,
                                                 c_ew1, eb1, c_ew3, eb3,
                                                 Gb, lists, counts);
    // pure down GEMM on G -> per-slot scratch (no atomics, no gather)
    mega_down<<<dim3(16, 16, 9), 256, 0, stream>>>(Gb, c_sw2, sb2, c_ew2, eb2,
                                                   Dscr, counts);
    // deterministic gate+sum into d_out (which already holds X1)
    ffn_combine<<<1024, 256, 0, stream>>>(Dscr, sE, sP, sG, (float*)d_out);
}